// Round 12
// baseline (222.136 us; speedup 1.0000x reference)
//
#include <hip/hip_runtime.h>
#include <hip/hip_fp16.h>

// out = sa*sb * (x @ q_b) @ q_a^T + bias
// Round 12: GEMM1 A-operand goes global->VGPR directly (per-wave loads + cvt,
// no LDS, no barrier coupling for the slow x stream); B keeps proven
// gload_lds + paired-row swizzle + two-barrier counted vmcnt(2) dbuf.
// GEMM2 reverted to R10's proven counted-vmcnt(8) two-barrier version.

#define M_TOT 8192
#define N_OUT 4096
#define K_IN  4096
#define RANK  512

typedef _Float16 f16x8 __attribute__((ext_vector_type(8)));
typedef float f32x4 __attribute__((ext_vector_type(4)));

#define WAIT_VM0() asm volatile("s_waitcnt vmcnt(0)" ::: "memory")
#define WAIT_VM2() asm volatile("s_waitcnt vmcnt(2)" ::: "memory")
#define WAIT_VM8() asm volatile("s_waitcnt vmcnt(8)" ::: "memory")
#define BARRIER() do { __builtin_amdgcn_s_barrier(); __builtin_amdgcn_sched_barrier(0); } while (0)

__device__ __forceinline__ void gload_lds16(const void* g, void* l) {
  __builtin_amdgcn_global_load_lds(
      (const __attribute__((address_space(1))) unsigned int*)g,
      (__attribute__((address_space(3))) unsigned int*)l, 16, 0, 0);
}

// ---- convert q_a int32 -> fp16 ----
__global__ void k_cvt_qa(const int4* __restrict__ q, ushort4* __restrict__ o, int n4) {
  int i = blockIdx.x * blockDim.x + threadIdx.x;
  if (i >= n4) return;
  int4 v = q[i];
  ushort4 r;
  r.x = __half_as_ushort(__float2half_rn((float)v.x));
  r.y = __half_as_ushort(__float2half_rn((float)v.y));
  r.z = __half_as_ushort(__float2half_rn((float)v.z));
  r.w = __half_as_ushort(__float2half_rn((float)v.w));
  o[i] = r;
}

// ---- transpose q_b [K_IN][RANK] i32 -> qbt [RANK][K_IN] fp16 ----
__global__ void k_transpose_qb(const int* __restrict__ qb, __half* __restrict__ qbt) {
  __shared__ __half tile[32][33];
  int tx = threadIdx.x & 31, ty = threadIdx.x >> 5;
  int k0 = blockIdx.x * 32, r0 = blockIdx.y * 32;
#pragma unroll
  for (int j = 0; j < 4; ++j)
    tile[ty + j * 8][tx] = __float2half_rn((float)qb[(size_t)(k0 + ty + j * 8) * RANK + r0 + tx]);
  __syncthreads();
#pragma unroll
  for (int j = 0; j < 4; ++j)
    qbt[(size_t)(r0 + ty + j * 8) * K_IN + k0 + tx] = tile[tx][ty + j * 8];
}

// ---- GEMM1: P[z] = x[:,z-chunk] @ qbt[:,z-chunk]^T ----
// BM=128 BN=256 BK=32, 512 thr = 8 waves (2m x 4n), wave 64x64, acc[4][4].
// A: per-wave global f32 loads -> cvt_pk -> f16 frags (no LDS, no barrier).
// B: gload_lds paired-row swizzle, dbuf 2x16KB, counted vmcnt(2) two-barrier.
__global__ __launch_bounds__(512, 4) void k_gemm1r(
    const float* __restrict__ X, const __half* __restrict__ Bt,
    __half* __restrict__ P) {
  __shared__ __align__(16) uint4 lds[2][1024];  // B only: 2 x 16 KB
  const int tid = threadIdx.x;
  const int lane = tid & 63, wid = tid >> 6;
  const int wm = wid & 1, wn = wid >> 1;          // 2m x 4n
  const int blk = blockIdx.x;
  const int xcd = blk & 7, m_t = blk >> 3;        // m_t 0..63
  const int z = xcd >> 1, n_t = xcd & 1;
  const int m0 = m_t * 128, n0 = n_t * 256;
  const int kbeg = z * (K_IN / 4);
  const int fr = lane & 15, fq = lane >> 4;

  f32x4 acc[4][4] = {};

  // A per-lane base: row m0 + wm*64 + fr (+ mi*16), cols kbeg + fq*8 (+ t*32)
  const float* abase = X + (size_t)(m0 + wm * 64 + fr) * K_IN + kbeg + fq * 8;

  auto stageB = [&](int kt, int buf) {
#pragma unroll
    for (int c = 0; c < 2; ++c) {
      int d = tid + 512 * c;
      int p = d >> 3, u = (d & 7) ^ (p & 7);
      gload_lds16(Bt + (size_t)(n0 + 2 * p + (u >> 2)) * K_IN + kbeg + kt * 32 + (u & 3) * 8,
                  &lds[buf][d]);
    }
  };

  stageB(0, 0);
  stageB(1, 1);
  WAIT_VM2();   // tile 0's 2 loads landed (tile 1's 2 in flight)
  BARRIER();

  const int NT = (K_IN / 4) / 32;  // 32
  for (int t = 0; t < NT; ++t) {
    // A: global -> regs -> f16 (compiler schedules loads early; waits per-use)
    f16x8 a[4];
#pragma unroll
    for (int mi = 0; mi < 4; ++mi) {
      const float* p = abase + (size_t)mi * 16 * K_IN + t * 32;
      f32x4 u0 = *(const f32x4*)p;
      f32x4 u1 = *(const f32x4*)(p + 4);
      union { __half2 h[4]; f16x8 v; } pa;
      pa.h[0] = __floats2half2_rn(u0[0], u0[1]);
      pa.h[1] = __floats2half2_rn(u0[2], u0[3]);
      pa.h[2] = __floats2half2_rn(u1[0], u1[1]);
      pa.h[3] = __floats2half2_rn(u1[2], u1[3]);
      a[mi] = pa.v;
    }
    // B frags from LDS (paired-row swizzle)
    const uint4* Bb = &lds[t & 1][0];
    f16x8 b[4];
#pragma unroll
    for (int ni = 0; ni < 4; ++ni) {
      int r = wn * 64 + ni * 16 + fr;
      int p = r >> 1;
      b[ni] = *(const f16x8*)&Bb[p * 8 + ((((r & 1) << 2) | fq) ^ (p & 7))];
    }
#pragma unroll
    for (int mi = 0; mi < 4; ++mi)
#pragma unroll
      for (int ni = 0; ni < 4; ++ni)
        acc[mi][ni] = __builtin_amdgcn_mfma_f32_16x16x32_f16(a[mi], b[ni], acc[mi][ni], 0, 0, 0);

    if (t == NT - 1) break;
    BARRIER();                       // all waves done reading lds[t&1]
    if (t + 2 < NT) {
      stageB(t + 2, t & 1);
      WAIT_VM2();                    // B(t+1)'s 2 loads retired; t+2's in flight
    } else {
      WAIT_VM0();
    }
    BARRIER();                       // B(t+1) visible to all
  }

  __half* Pz = P + (size_t)z * M_TOT * RANK;
#pragma unroll
  for (int mi = 0; mi < 4; ++mi)
#pragma unroll
    for (int ni = 0; ni < 4; ++ni) {
      int col = n0 + wn * 64 + ni * 16 + fr;
      int rbase = m0 + wm * 64 + mi * 16 + fq * 4;
#pragma unroll
      for (int j = 0; j < 4; ++j)
        Pz[(size_t)(rbase + j) * RANK + col] = __float2half_rn(acc[mi][ni][j]);
    }
}

// ---- reduce: t = f16(sum_z P[z]), f32 math, 8 halfs/thread ----
__global__ void k_reduce_t(const uint4* __restrict__ P, uint4* __restrict__ T8, int n8) {
  int i = blockIdx.x * blockDim.x + threadIdx.x;
  if (i >= n8) return;
  float2 f[4] = {};
#pragma unroll
  for (int zz = 0; zz < 4; ++zz) {
    uint4 v = P[(size_t)zz * n8 + i];
    const __half2* h = (const __half2*)&v;
#pragma unroll
    for (int j = 0; j < 4; ++j) {
      float2 g = __half22float2(h[j]);
      f[j].x += g.x; f[j].y += g.y;
    }
  }
  uint4 r;
  __half2* o = (__half2*)&r;
#pragma unroll
  for (int j = 0; j < 4; ++j) o[j] = __floats2half2_rn(f[j].x, f[j].y);
  T8[i] = r;
}

// ---- GEMM2: out = t @ qa^T * scale + bias (R10 proven version) ----
__global__ __launch_bounds__(256, 2) void k_gemm2(
    const __half* __restrict__ T, const __half* __restrict__ QA,
    const float* __restrict__ sa, const float* __restrict__ sb,
    const float* __restrict__ bias, float* __restrict__ Out) {
  __shared__ __align__(16) uint4 lds[2][2048];
  const int tid = threadIdx.x;
  const int lane = tid & 63, wid = tid >> 6, wm = wid & 1, wn = wid >> 1;
  const int flat = blockIdx.x;
  const int xcd = flat & 7, local = flat >> 3;
  const int n_t = xcd * 4 + (local & 3);
  const int m_t = local >> 2;
  const int m0 = m_t * 128, n0 = n_t * 128;
  const int fr = lane & 15, fq = lane >> 4;

  f32x4 acc[4][4] = {};

  auto stage = [&](int kt, int buf) {
#pragma unroll
    for (int c = 0; c < 4; ++c) {
      int d = tid + 256 * c;
      int r = d >> 3, s = (d & 7) ^ (r & 7);
      gload_lds16(T + (size_t)(m0 + r) * RANK + kt * 64 + s * 8, &lds[buf][d]);
    }
#pragma unroll
    for (int c = 0; c < 4; ++c) {
      int d = tid + 256 * c;
      int r = d >> 3, s = (d & 7) ^ (r & 7);
      gload_lds16(QA + (size_t)(n0 + r) * RANK + kt * 64 + s * 8, &lds[buf][1024 + d]);
    }
  };

  stage(0, 0);
  stage(1, 1);
  WAIT_VM8();
  BARRIER();

  const int NT = RANK / 64;
  for (int t = 0; t < NT; ++t) {
    const int cur = t & 1;
#pragma unroll
    for (int kk = 0; kk < 2; ++kk) {
      int s = kk * 4 + fq;
      f16x8 a[4], b[4];
#pragma unroll
      for (int mi = 0; mi < 4; ++mi) {
        int r = wm * 64 + mi * 16 + fr;
        a[mi] = *(const f16x8*)&lds[cur][r * 8 + (s ^ (r & 7))];
      }
#pragma unroll
      for (int ni = 0; ni < 4; ++ni) {
        int n = wn * 64 + ni * 16 + fr;
        b[ni] = *(const f16x8*)&lds[cur][1024 + n * 8 + (s ^ (n & 7))];
      }
#pragma unroll
      for (int mi = 0; mi < 4; ++mi)
#pragma unroll
        for (int ni = 0; ni < 4; ++ni)
          acc[mi][ni] = __builtin_amdgcn_mfma_f32_16x16x32_f16(a[mi], b[ni], acc[mi][ni], 0, 0, 0);
    }
    if (t == NT - 1) break;
    BARRIER();
    if (t + 2 < NT) {
      stage(t + 2, cur);
      WAIT_VM8();
    } else {
      WAIT_VM0();
    }
    BARRIER();
  }

  const float scale = sa[0] * sb[0];
#pragma unroll
  for (int mi = 0; mi < 4; ++mi)
#pragma unroll
    for (int ni = 0; ni < 4; ++ni) {
      int col = n0 + wn * 64 + ni * 16 + fr;
      float bv = bias[col];
      int rbase = m0 + wm * 64 + mi * 16 + fq * 4;
#pragma unroll
      for (int j = 0; j < 4; ++j)
        Out[(size_t)(rbase + j) * N_OUT + col] = acc[mi][ni][j] * scale + bv;
    }
}

extern "C" void kernel_launch(void* const* d_in, const int* in_sizes, int n_in,
                              void* d_out, int out_size, void* d_ws, size_t ws_size,
                              hipStream_t stream) {
  const float* x    = (const float*)d_in[0];
  const int*   qa   = (const int*)d_in[1];
  const int*   qb   = (const int*)d_in[2];
  const float* sa   = (const float*)d_in[3];
  const float* sb   = (const float*)d_in[4];
  const float* bias = (const float*)d_in[5];
  float* out = (float*)d_out;

  // layout: qa_h 4MB | qbt 4MB | t 8MB | part 32MB  = 48 MiB
  char* ws = (char*)d_ws;
  __half* qa_h = (__half*)ws;
  __half* qbt  = (__half*)(ws + (4u << 20));
  __half* t    = (__half*)(ws + (8u << 20));
  __half* part = (__half*)(ws + (16u << 20));

  k_cvt_qa<<<2048, 256, 0, stream>>>((const int4*)qa, (ushort4*)qa_h, (N_OUT * RANK) / 4);
  dim3 tg(K_IN / 32, RANK / 32);
  k_transpose_qb<<<tg, 256, 0, stream>>>(qb, qbt);

  k_gemm1r<<<512, 512, 0, stream>>>(x, qbt, part);

  const int n8 = M_TOT * RANK / 8;  // 524288
  k_reduce_t<<<n8 / 256, 256, 0, stream>>>((const uint4*)part, (uint4*)t, n8);

  k_gemm2<<<2048, 256, 0, stream>>>(t, qa_h, sa, sb, bias, out);
}

// Round 13
// 142.341 us; speedup vs baseline: 1.5606x; 1.5606x over previous
//
#include <hip/hip_runtime.h>
#include <hip/hip_fp16.h>

// out = sa*sb * (x @ q_b) @ q_a^T + bias
// Round 13: GEMM1 "A-batch" staging — each thread loads 64 B CONTIGUOUS of x
// (per-row DRAM runs 512 B vs 128 B before; theory: row-activation-bound HBM),
// covering 4 K-tiles at once; cvt to f16; one LDS write per 4 tiles.
// B: R10's proven gload_lds paired-row dbuf + counted vmcnt ledger.
// GEMM2 / reduce / pre-passes: R10 verbatim (proven).

#define M_TOT 8192
#define N_OUT 4096
#define K_IN  4096
#define RANK  512

typedef _Float16 f16x8 __attribute__((ext_vector_type(8)));
typedef float f32x4 __attribute__((ext_vector_type(4)));

#define WAIT_VM0() asm volatile("s_waitcnt vmcnt(0)" ::: "memory")
#define WAIT_VM2() asm volatile("s_waitcnt vmcnt(2)" ::: "memory")
#define WAIT_VM6() asm volatile("s_waitcnt vmcnt(6)" ::: "memory")
#define WAIT_VM8() asm volatile("s_waitcnt vmcnt(8)" ::: "memory")
#define WAIT_LGKM0() asm volatile("s_waitcnt lgkmcnt(0)" ::: "memory")
#define BARRIER() do { __builtin_amdgcn_s_barrier(); __builtin_amdgcn_sched_barrier(0); } while (0)

__device__ __forceinline__ void gload_lds16(const void* g, void* l) {
  __builtin_amdgcn_global_load_lds(
      (const __attribute__((address_space(1))) unsigned int*)g,
      (__attribute__((address_space(3))) unsigned int*)l, 16, 0, 0);
}

// ---- convert q_a int32 -> fp16 ----
__global__ void k_cvt_qa(const int4* __restrict__ q, ushort4* __restrict__ o, int n4) {
  int i = blockIdx.x * blockDim.x + threadIdx.x;
  if (i >= n4) return;
  int4 v = q[i];
  ushort4 r;
  r.x = __half_as_ushort(__float2half_rn((float)v.x));
  r.y = __half_as_ushort(__float2half_rn((float)v.y));
  r.z = __half_as_ushort(__float2half_rn((float)v.z));
  r.w = __half_as_ushort(__float2half_rn((float)v.w));
  o[i] = r;
}

// ---- transpose q_b [K_IN][RANK] i32 -> qbt [RANK][K_IN] fp16 ----
__global__ void k_transpose_qb(const int* __restrict__ qb, __half* __restrict__ qbt) {
  __shared__ __half tile[32][33];
  int tx = threadIdx.x & 31, ty = threadIdx.x >> 5;
  int k0 = blockIdx.x * 32, r0 = blockIdx.y * 32;
#pragma unroll
  for (int j = 0; j < 4; ++j)
    tile[ty + j * 8][tx] = __float2half_rn((float)qb[(size_t)(k0 + ty + j * 8) * RANK + r0 + tx]);
  __syncthreads();
#pragma unroll
  for (int j = 0; j < 4; ++j)
    qbt[(size_t)(r0 + ty + j * 8) * K_IN + k0 + tx] = tile[tx][ty + j * 8];
}

// ---- GEMM1: P[z] = x[:,z-chunk] @ qbt[:,z-chunk]^T ----
// BM=64 BN=256 BK=32, 512 thr = 8 waves (2m x 4n), wave 32x64, acc[2][4].
// A: reg-batched (4 tiles / 512 B per-row runs), single-buf 4-subtile LDS.
// B: gload_lds paired-row swizzle dbuf. Counted-vmcnt ledger (see waits).
__global__ __launch_bounds__(512, 2) void k_gemm1b(
    const float* __restrict__ X, const __half* __restrict__ Bt,
    __half* __restrict__ P) {
  __shared__ __align__(16) uint4 Al[1024];     // 4 subtiles x (64r x 4 slots) = 16 KB
  __shared__ __align__(16) uint4 Bl[2][1024];  // dbuf: 256r x 4 slots = 2 x 16 KB
  const int tid = threadIdx.x;
  const int lane = tid & 63, wid = tid >> 6;
  const int wm = wid & 1, wn = wid >> 1;        // 2m x 4n
  const int blk = blockIdx.x;
  const int xcd = blk & 7, m_t = blk >> 3;      // m_t 0..127
  const int z = xcd >> 1, n_t = xcd & 1;
  const int m0 = m_t * 64, n0 = n_t * 256;
  const int kbeg = z * (K_IN / 4);
  const int fr = lane & 15, fq = lane >> 4;

  f32x4 acc[2][4] = {};

  // A: thread -> row ar_=tid>>3, 64 B chunk c8=tid&7 (cols c8*16..+15)
  const int ar_ = tid >> 3, c8 = tid & 7;
  const float* abase = X + (size_t)(m0 + ar_) * K_IN + kbeg + c8 * 16;
  const int ast = c8 >> 1, ahalf = c8 & 1;
  const int ap = ar_ >> 1, arb = (ar_ & 1) << 2, apx = ap & 7;
  const int aw0 = ast * 256 + ap * 8 + ((arb | (ahalf * 2 + 0)) ^ apx);
  const int aw1 = ast * 256 + ap * 8 + ((arb | (ahalf * 2 + 1)) ^ apx);

  float4 arg[4];
  auto loadA = [&](int batch) {  // batch covers cols batch*128 .. +127
#pragma unroll
    for (int i = 0; i < 4; ++i)
      arg[i] = *(const float4*)(abase + batch * 128 + i * 4);
  };
  auto writeA = [&]() {
    union { __half2 h[4]; uint4 u; } q0, q1;
    q0.h[0] = __floats2half2_rn(arg[0].x, arg[0].y);
    q0.h[1] = __floats2half2_rn(arg[0].z, arg[0].w);
    q0.h[2] = __floats2half2_rn(arg[1].x, arg[1].y);
    q0.h[3] = __floats2half2_rn(arg[1].z, arg[1].w);
    q1.h[0] = __floats2half2_rn(arg[2].x, arg[2].y);
    q1.h[1] = __floats2half2_rn(arg[2].z, arg[2].w);
    q1.h[2] = __floats2half2_rn(arg[3].x, arg[3].y);
    q1.h[3] = __floats2half2_rn(arg[3].z, arg[3].w);
    Al[aw0] = q0.u;
    Al[aw1] = q1.u;
  };
  auto stageB = [&](int kt, int buf) {
#pragma unroll
    for (int c = 0; c < 2; ++c) {
      int d = tid + 512 * c;
      int p = d >> 3, u = (d & 7) ^ (p & 7);
      gload_lds16(Bt + (size_t)(n0 + 2 * p + (u >> 2)) * K_IN + kbeg + kt * 32 + (u & 3) * 8,
                  &Bl[buf][d]);
    }
  };

  // prologue: A batch0 (4 loads) + B0,B1 (2+2); vmcnt(2) retires A4+B0.
  loadA(0);
  stageB(0, 0);
  stageB(1, 1);
  WAIT_VM2();
  writeA();
  WAIT_LGKM0();
  BARRIER();

  const int NT = (K_IN / 4) / 32;  // 32
  for (int t = 0; t < NT; ++t) {
    const int lt = t & 3;
    // compute tile t: A from subtile lt, B from Bl[t&1]
    {
      const uint4* Bb = &Bl[t & 1][0];
      f16x8 a[2], b[4];
#pragma unroll
      for (int mi = 0; mi < 2; ++mi) {
        int r = wm * 32 + mi * 16 + fr;
        int p = r >> 1;
        a[mi] = *(const f16x8*)&Al[lt * 256 + p * 8 + ((((r & 1) << 2) | fq) ^ (p & 7))];
      }
#pragma unroll
      for (int ni = 0; ni < 4; ++ni) {
        int r = wn * 64 + ni * 16 + fr;
        int p = r >> 1;
        b[ni] = *(const f16x8*)&Bb[p * 8 + ((((r & 1) << 2) | fq) ^ (p & 7))];
      }
#pragma unroll
      for (int mi = 0; mi < 2; ++mi)
#pragma unroll
        for (int ni = 0; ni < 4; ++ni)
          acc[mi][ni] = __builtin_amdgcn_mfma_f32_16x16x32_f16(a[mi], b[ni], acc[mi][ni], 0, 0, 0);
    }
    if (t == NT - 1) break;
    BARRIER();                           // all waves done reading Bl[t&1] (and Al if lt==3)
    if (t + 2 < NT) stageB(t + 2, t & 1);
    if (lt == 1 && t + 4 < NT) loadA((t + 4) >> 2);  // issue next A-batch (regs)
    // counted waits (ledger: A issued lt==1, retired lt==3; B staged t+2 each tile)
    if (lt == 3) {
      WAIT_VM2();                        // retires A4 + B(t+1); leaves B(t+2)
      writeA();                          // publish next A-batch
      WAIT_LGKM0();
    } else if ((lt == 1 || lt == 2) && t <= 26) {
      WAIT_VM6();                        // retires B(t+1); leaves B(t+2)+A4
    } else if (t <= 29) {
      WAIT_VM2();                        // retires B(t+1); leaves B(t+2)
    } else {
      WAIT_VM0();                        // t==30 tail
    }
    BARRIER();
  }

  __half* Pz = P + (size_t)z * M_TOT * RANK;
#pragma unroll
  for (int mi = 0; mi < 2; ++mi)
#pragma unroll
    for (int ni = 0; ni < 4; ++ni) {
      int col = n0 + wn * 64 + ni * 16 + fr;
      int rbase = m0 + wm * 32 + mi * 16 + fq * 4;
#pragma unroll
      for (int j = 0; j < 4; ++j)
        Pz[(size_t)(rbase + j) * RANK + col] = __float2half_rn(acc[mi][ni][j]);
    }
}

// ---- reduce: t = f16(sum_z P[z]), f32 math, 8 halfs/thread ----
__global__ void k_reduce_t(const uint4* __restrict__ P, uint4* __restrict__ T8, int n8) {
  int i = blockIdx.x * blockDim.x + threadIdx.x;
  if (i >= n8) return;
  float2 f[4] = {};
#pragma unroll
  for (int zz = 0; zz < 4; ++zz) {
    uint4 v = P[(size_t)zz * n8 + i];
    const __half2* h = (const __half2*)&v;
#pragma unroll
    for (int j = 0; j < 4; ++j) {
      float2 g = __half22float2(h[j]);
      f[j].x += g.x; f[j].y += g.y;
    }
  }
  uint4 r;
  __half2* o = (__half2*)&r;
#pragma unroll
  for (int j = 0; j < 4; ++j) o[j] = __floats2half2_rn(f[j].x, f[j].y);
  T8[i] = r;
}

// ---- GEMM2: out = t @ qa^T * scale + bias (R10 proven version) ----
__global__ __launch_bounds__(256, 2) void k_gemm2(
    const __half* __restrict__ T, const __half* __restrict__ QA,
    const float* __restrict__ sa, const float* __restrict__ sb,
    const float* __restrict__ bias, float* __restrict__ Out) {
  __shared__ __align__(16) uint4 lds[2][2048];
  const int tid = threadIdx.x;
  const int lane = tid & 63, wid = tid >> 6, wm = wid & 1, wn = wid >> 1;
  const int flat = blockIdx.x;
  const int xcd = flat & 7, local = flat >> 3;
  const int n_t = xcd * 4 + (local & 3);
  const int m_t = local >> 2;
  const int m0 = m_t * 128, n0 = n_t * 128;
  const int fr = lane & 15, fq = lane >> 4;

  f32x4 acc[4][4] = {};

  auto stage = [&](int kt, int buf) {
#pragma unroll
    for (int c = 0; c < 4; ++c) {
      int d = tid + 256 * c;
      int r = d >> 3, s = (d & 7) ^ (r & 7);
      gload_lds16(T + (size_t)(m0 + r) * RANK + kt * 64 + s * 8, &lds[buf][d]);
    }
#pragma unroll
    for (int c = 0; c < 4; ++c) {
      int d = tid + 256 * c;
      int r = d >> 3, s = (d & 7) ^ (r & 7);
      gload_lds16(QA + (size_t)(n0 + r) * RANK + kt * 64 + s * 8, &lds[buf][1024 + d]);
    }
  };

  stage(0, 0);
  stage(1, 1);
  WAIT_VM8();
  BARRIER();

  const int NT = RANK / 64;
  for (int t = 0; t < NT; ++t) {
    const int cur = t & 1;
#pragma unroll
    for (int kk = 0; kk < 2; ++kk) {
      int s = kk * 4 + fq;
      f16x8 a[4], b[4];
#pragma unroll
      for (int mi = 0; mi < 4; ++mi) {
        int r = wm * 64 + mi * 16 + fr;
        a[mi] = *(const f16x8*)&lds[cur][r * 8 + (s ^ (r & 7))];
      }
#pragma unroll
      for (int ni = 0; ni < 4; ++ni) {
        int n = wn * 64 + ni * 16 + fr;
        b[ni] = *(const f16x8*)&lds[cur][1024 + n * 8 + (s ^ (n & 7))];
      }
#pragma unroll
      for (int mi = 0; mi < 4; ++mi)
#pragma unroll
        for (int ni = 0; ni < 4; ++ni)
          acc[mi][ni] = __builtin_amdgcn_mfma_f32_16x16x32_f16(a[mi], b[ni], acc[mi][ni], 0, 0, 0);
    }
    if (t == NT - 1) break;
    BARRIER();
    if (t + 2 < NT) {
      stage(t + 2, cur);
      WAIT_VM8();
    } else {
      WAIT_VM0();
    }
    BARRIER();
  }

  const float scale = sa[0] * sb[0];
#pragma unroll
  for (int mi = 0; mi < 4; ++mi)
#pragma unroll
    for (int ni = 0; ni < 4; ++ni) {
      int col = n0 + wn * 64 + ni * 16 + fr;
      float bv = bias[col];
      int rbase = m0 + wm * 64 + mi * 16 + fq * 4;
#pragma unroll
      for (int j = 0; j < 4; ++j)
        Out[(size_t)(rbase + j) * N_OUT + col] = acc[mi][ni][j] * scale + bv;
    }
}

extern "C" void kernel_launch(void* const* d_in, const int* in_sizes, int n_in,
                              void* d_out, int out_size, void* d_ws, size_t ws_size,
                              hipStream_t stream) {
  const float* x    = (const float*)d_in[0];
  const int*   qa   = (const int*)d_in[1];
  const int*   qb   = (const int*)d_in[2];
  const float* sa   = (const float*)d_in[3];
  const float* sb   = (const float*)d_in[4];
  const float* bias = (const float*)d_in[5];
  float* out = (float*)d_out;

  // layout: qa_h 4MB | qbt 4MB | t 8MB | part 32MB  = 48 MiB
  char* ws = (char*)d_ws;
  __half* qa_h = (__half*)ws;
  __half* qbt  = (__half*)(ws + (4u << 20));
  __half* t    = (__half*)(ws + (8u << 20));
  __half* part = (__half*)(ws + (16u << 20));

  k_cvt_qa<<<2048, 256, 0, stream>>>((const int4*)qa, (ushort4*)qa_h, (N_OUT * RANK) / 4);
  dim3 tg(K_IN / 32, RANK / 32);
  k_transpose_qb<<<tg, 256, 0, stream>>>(qb, qbt);

  k_gemm1b<<<1024, 512, 0, stream>>>(x, qbt, part);

  const int n8 = M_TOT * RANK / 8;  // 524288
  k_reduce_t<<<n8 / 256, 256, 0, stream>>>((const uint4*)part, (uint4*)t, n8);

  k_gemm2<<<2048, 256, 0, stream>>>(t, qa_h, sa, sb, bias, out);
}